// Round 16
// baseline (106.782 us; speedup 1.0000x reference)
//
#include <hip/hip_runtime.h>
#include <hip/hip_bf16.h>
#include <math.h>

#define NP 256
#define DD 65536

// ws float offsets
#define WS_SQ    65536          // 256
#define WS_KSUM  (65536 + 256)  // 256
#define WS_SIG   66048          // [0]=sigma [1]=1/(2s^2) [2]=1/s^2
// byte offsets
#define XBTF_BYTE_OFF  33818656u        // der B frags (d,k=i): 33,554,432 B
#define KBF_BYTE_OFF   67373088u        // der A frags (j,k=i, diag-folded): 131,072 B
#define WS_NEED_MID    67504160u
// gram K-partials: 256 slabs x 256x256 f32 = 64 MB = exactly d_out's der region.
// Only LOWER-TRIANGLE 64x64 tiles are written (10 of 16 per slab; upper tiles are
// bitwise mirrors). Written by fused_gram_cast, read by gram_reduce (lower tiles
// only), then the whole region is overwritten by der_mfma. Deterministic.

typedef __attribute__((ext_vector_type(8))) short bf16x8;
typedef __attribute__((ext_vector_type(16))) float f32x16;

static __device__ __forceinline__ unsigned short f2bf(float f) {
    __hip_bfloat16 h = __float2bfloat16(f);
    return *reinterpret_cast<unsigned short*>(&h);
}

// ---------------- fused cast+gram v7: symmetric, lower-tri P, 2 blocks/CU ----------------
// grid (512): zc -> z = zc>>1 (K-chunk of 256 d), half = zc&1 (output rows half*128..+128).
// 1024 thr = 16 waves (wy2 = w>>2: 32-row group in half, wx = w&3: 64-col group),
// wave = 32x64 (acc[2] of 32x32). Both blocks of a z stage the same full 256-row slab
// (X re-read L3-absorbed). Waves with tile above the diagonal skip the P store.
// XbTF emission split between the two halves.
__global__ __launch_bounds__(1024) void fused_gram_cast(const float* __restrict__ X,
                                                        float* __restrict__ P,
                                                        unsigned short* __restrict__ XbTF) {
    __shared__ __align__(16) unsigned short Afrag[2][32 * 512];  // 2 x 32 KB
    const int t = threadIdx.x;
    const int lane = t & 63, w = t >> 6;
    const int wy2 = w >> 2, wx = w & 3;
    const int zc = blockIdx.x;
    const int z = zc >> 1, half = zc & 1;
    const int dbase = z * 256;
    const int srow = t >> 2;              // 0..255 staging row
    const int sdc  = (t & 3) * 16;        // staging d-col (16 floats = one k16 chunk)

    f32x16 acc[2] = {};
    float4 p0, p1, p2, p3;

    {   // prologue loads (sub 0)
        const float4* s = (const float4*)&X[(size_t)srow * DD + dbase + sdc];
        p0 = s[0]; p1 = s[1]; p2 = s[2]; p3 = s[3];
    }
    for (int sub = 0; sub < 4; ++sub) {
        unsigned short* buf = Afrag[sub & 1];
        {   // stage regs -> frag layout (2 x b128 per thread)
            union { unsigned short u[16]; bf16x8 v[2]; } a;
            a.u[0]  = f2bf(p0.x); a.u[1]  = f2bf(p0.y); a.u[2]  = f2bf(p0.z); a.u[3]  = f2bf(p0.w);
            a.u[4]  = f2bf(p1.x); a.u[5]  = f2bf(p1.y); a.u[6]  = f2bf(p1.z); a.u[7]  = f2bf(p1.w);
            a.u[8]  = f2bf(p2.x); a.u[9]  = f2bf(p2.y); a.u[10] = f2bf(p2.z); a.u[11] = f2bf(p2.w);
            a.u[12] = f2bf(p3.x); a.u[13] = f2bf(p3.y); a.u[14] = f2bf(p3.z); a.u[15] = f2bf(p3.w);
            int ch = (srow >> 5) * 4 + (sdc >> 4);
            *(bf16x8*)&buf[ch * 512 +       (srow & 31) * 8] = a.v[0];
            *(bf16x8*)&buf[ch * 512 + 256 + (srow & 31) * 8] = a.v[1];
        }
        __syncthreads();
        if (sub < 3) {                    // prefetch next sub BEFORE compute
            const float4* s = (const float4*)&X[(size_t)srow * DD + dbase + (sub + 1) * 64 + sdc];
            p0 = s[0]; p1 = s[1]; p2 = s[2]; p3 = s[3];
        }
#pragma unroll
        for (int ksi = 0; ksi < 4; ksi++) {
            bf16x8 a = *(const bf16x8*)&buf[((half * 4 + wy2) * 4 + ksi) * 512 + lane * 8];
            bf16x8 b[2];
#pragma unroll
            for (int u = 0; u < 2; u++)
                b[u] = *(const bf16x8*)&buf[((wx * 2 + u) * 4 + ksi) * 512 + lane * 8];
#pragma unroll
            for (int u = 0; u < 2; u++)
                acc[u] = __builtin_amdgcn_mfma_f32_32x32x16_bf16(a, b[u], acc[u], 0, 0, 0);
        }
        // ---- XbTF emission: 2048 b128 outputs per z-sub; this half does 1024 ----
        {
            int oid = t + half * 1024;
            int ch_o = oid >> 6, slot = oid & 63;
            int db = ch_o >> 4, i16 = ch_o & 15;
            int dl = db * 32 + (slot & 31);
            int ibase = i16 * 16 + (slot >> 5) * 8;
            int ch_in = (ibase >> 5) * 4 + (dl >> 4);
            int hf = ((dl >> 3) & 1) * 256;
            int dlo = dl & 7;
            union { unsigned short u[8]; bf16x8 v; } o;
#pragma unroll
            for (int e = 0; e < 8; e++)
                o.u[e] = buf[ch_in * 512 + hf + ((ibase + e) & 31) * 8 + dlo];
            size_t gch = (size_t)(z * 8 + sub * 2 + db) * 16 + i16;
            *(bf16x8*)&XbTF[gch * 512 + slot * 8] = o.v;
        }
    }
    // ---- write P[z] lower-triangle tiles only ----
    const int ty_t = half * 2 + (wy2 >> 1);   // 64-row tile index
    if (ty_t >= wx) {
        const int hl = lane >> 5, lr = lane & 31;
        float* Pz = P + (size_t)z * 65536;
        const int ibt = half * 128 + wy2 * 32 + 4 * hl;
#pragma unroll
        for (int u = 0; u < 2; u++) {
            int jc = wx * 64 + u * 32 + lr;
#pragma unroll
            for (int r = 0; r < 16; r++) {
                int ir = ibt + (r & 3) + 8 * (r >> 2);
                Pz[ir * 256 + jc] = acc[u][r];
            }
        }
    }
}

// ---------------- reduce 256 K-partials (lower tiles) -> full G ----------------
// grid 160 x 64 thr: 10 lower 64x64 tiles x 1024 float4 slots.
__global__ __launch_bounds__(64) void gram_reduce(const float* __restrict__ P,
                                                  float* __restrict__ G) {
    const int bid = blockIdx.x;               // 0..159
    const int tile = bid >> 4;                // 0..9 (lower-tri row-major)
    const int slot = (bid & 15) * 64 + threadIdx.x;   // 0..1023
    int ty, tx;
    if (tile < 1)      { ty = 0; tx = tile; }
    else if (tile < 3) { ty = 1; tx = tile - 1; }
    else if (tile < 6) { ty = 2; tx = tile - 3; }
    else               { ty = 3; tx = tile - 6; }
    const int il = slot >> 4;                 // 0..63
    const int jq = (slot & 15) * 4;
    const int i = ty * 64 + il;
    const int j = tx * 64 + jq;
    const int e4 = i * 64 + (j >> 2);
    const float4* P4 = (const float4*)P;
    float4 s0 = {0.f, 0.f, 0.f, 0.f}, s1 = {0.f, 0.f, 0.f, 0.f};
#pragma unroll 4
    for (int z = 0; z < 256; z += 2) {
        float4 a = P4[(size_t)z * 16384 + e4];
        float4 b = P4[(size_t)(z + 1) * 16384 + e4];
        s0.x += a.x; s0.y += a.y; s0.z += a.z; s0.w += a.w;
        s1.x += b.x; s1.y += b.y; s1.z += b.z; s1.w += b.w;
    }
    float4 s = {s0.x + s1.x, s0.y + s1.y, s0.z + s1.z, s0.w + s1.w};
    ((float4*)G)[e4] = s;
    if (ty > tx) {                            // mirror into upper triangle
        G[(j + 0) * 256 + i] = s.x;
        G[(j + 1) * 256 + i] = s.y;
        G[(j + 2) * 256 + i] = s.z;
        G[(j + 3) * 256 + i] = s.w;
    }
}

// ---------------- median via 2-level histogram select, one launch ----------------
#define L1BINS 2048
__global__ __launch_bounds__(1024) void median_sigma_kernel(const float* __restrict__ G,
                                                            const float* __restrict__ EMA,
                                                            float* __restrict__ sq_ws,
                                                            float* __restrict__ sig,
                                                            float* __restrict__ sigma_out) {
    __shared__ unsigned hist[16][L1BINS];       // 128 KB, per-wave copies
    __shared__ unsigned scanw[48];
    __shared__ float sq_l[256];
    __shared__ float redf[32];
    __shared__ unsigned s_b0, s_b1, s_base0;
    __shared__ float s_v0, s_v1;
    const int t = threadIdx.x;
    const int lane = t & 63, wid = t >> 6;

    if (t < 256) { float v = G[t * (NP + 1)]; sq_l[t] = v; sq_ws[t] = v; }
    __syncthreads();
    const float4* G4 = (const float4*)G;

    float mn = 3.4e38f, mx = 0.f;
    for (int q = 0; q < 16; q++) {
        int idx4 = q * 1024 + t;
        float4 g = G4[idx4];
        int i = idx4 >> 6, jb = (idx4 * 4) & 255;
        float si = sq_l[i];
        float d0 = fmaxf(si + sq_l[jb + 0] - 2.f * g.x, 0.f);
        float d1 = fmaxf(si + sq_l[jb + 1] - 2.f * g.y, 0.f);
        float d2 = fmaxf(si + sq_l[jb + 2] - 2.f * g.z, 0.f);
        float d3 = fmaxf(si + sq_l[jb + 3] - 2.f * g.w, 0.f);
        mn = fminf(mn, fminf(fminf(d0, d1), fminf(d2, d3)));
        mx = fmaxf(mx, fmaxf(fmaxf(d0, d1), fmaxf(d2, d3)));
    }
    for (int off = 32; off; off >>= 1) {
        mn = fminf(mn, __shfl_down(mn, off));
        mx = fmaxf(mx, __shfl_down(mx, off));
    }
    if (lane == 0) { redf[wid] = mn; redf[16 + wid] = mx; }
    __syncthreads();
    if (t == 0) {
        float a = redf[0], b = redf[16];
        for (int i = 1; i < 16; i++) { a = fminf(a, redf[i]); b = fmaxf(b, redf[16 + i]); }
        redf[0] = a; redf[16] = b;
    }
    __syncthreads();
    const float mn0 = redf[0];
    const float rng = redf[16] - mn0;
    float med = mn0;

    if (rng > 0.f) {
        const float scale1 = (float)L1BINS * (1.f - 1e-6f) / rng;
        const float binw1 = rng / ((float)L1BINS * (1.f - 1e-6f));
        {
            uint4* h4 = (uint4*)hist;
            uint4 zz = {0u, 0u, 0u, 0u};
            for (int i = t; i < 16 * L1BINS / 4; i += 1024) h4[i] = zz;
        }
        __syncthreads();
        for (int q = 0; q < 16; q++) {
            int idx4 = q * 1024 + t;
            float4 g = G4[idx4];
            int i = idx4 >> 6, jb = (idx4 * 4) & 255;
            float si = sq_l[i];
            float dd[4];
            dd[0] = fmaxf(si + sq_l[jb + 0] - 2.f * g.x, 0.f);
            dd[1] = fmaxf(si + sq_l[jb + 1] - 2.f * g.y, 0.f);
            dd[2] = fmaxf(si + sq_l[jb + 2] - 2.f * g.z, 0.f);
            dd[3] = fmaxf(si + sq_l[jb + 3] - 2.f * g.w, 0.f);
#pragma unroll
            for (int e = 0; e < 4; e++) {
                int b = (int)((dd[e] - mn0) * scale1);
                b = min(max(b, 0), L1BINS - 1);
                atomicAdd(&hist[wid][b], 1u);
            }
        }
        __syncthreads();
        unsigned c0 = 0, c1 = 0;
#pragma unroll
        for (int wv = 0; wv < 16; wv++) { c0 += hist[wv][2 * t]; c1 += hist[wv][2 * t + 1]; }
        unsigned p = c0 + c1;
        unsigned v = p;
        for (int off = 1; off < 64; off <<= 1) {
            unsigned u = __shfl_up(v, off);
            if (lane >= off) v += u;
        }
        if (lane == 63) scanw[wid] = v;
        __syncthreads();
        if (t < 16) {
            unsigned s = 0;
            for (int i = 0; i <= t; i++) s += scanw[i];
            scanw[16 + t] = s;
        }
        __syncthreads();
        unsigned incl = v + ((wid == 0) ? 0u : scanw[16 + wid - 1]);
        unsigned excl = incl - p;
        if (excl <= 32767u && 32767u < excl + c0) { s_b0 = 2 * t;     s_base0 = excl; }
        else if (excl + c0 <= 32767u && 32767u < incl) { s_b0 = 2 * t + 1; s_base0 = excl + c0; }
        if (excl <= 32768u && 32768u < excl + c0) s_b1 = 2 * t;
        else if (excl + c0 <= 32768u && 32768u < incl) s_b1 = 2 * t + 1;
        __syncthreads();
        const unsigned b0 = s_b0, b1 = s_b1, base0 = s_base0;
        const float lo2 = mn0 + (float)b0 * binw1;
        const float span = (float)(b1 + 1 - b0) * binw1;
        const float scale2 = (float)L1BINS * (1.f - 1e-6f) / span;
        const float binw2 = span / ((float)L1BINS * (1.f - 1e-6f));
        {
            uint4* h4 = (uint4*)hist;
            uint4 zz = {0u, 0u, 0u, 0u};
            for (int i = t; i < 16 * L1BINS / 4; i += 1024) h4[i] = zz;
        }
        __syncthreads();
        for (int q = 0; q < 16; q++) {
            int idx4 = q * 1024 + t;
            float4 g = G4[idx4];
            int i = idx4 >> 6, jb = (idx4 * 4) & 255;
            float si = sq_l[i];
            float dd[4];
            dd[0] = fmaxf(si + sq_l[jb + 0] - 2.f * g.x, 0.f);
            dd[1] = fmaxf(si + sq_l[jb + 1] - 2.f * g.y, 0.f);
            dd[2] = fmaxf(si + sq_l[jb + 2] - 2.f * g.z, 0.f);
            dd[3] = fmaxf(si + sq_l[jb + 3] - 2.f * g.w, 0.f);
#pragma unroll
            for (int e = 0; e < 4; e++) {
                int b = (int)((dd[e] - mn0) * scale1);
                b = min(max(b, 0), L1BINS - 1);
                if (b >= (int)b0 && b <= (int)b1) {
                    int sb = (int)((dd[e] - lo2) * scale2);
                    sb = min(max(sb, 0), L1BINS - 1);
                    atomicAdd(&hist[wid][sb], 1u);
                }
            }
        }
        __syncthreads();
        const unsigned r0 = 32767u - base0, r1 = 32768u - base0;
        c0 = 0; c1 = 0;
#pragma unroll
        for (int wv = 0; wv < 16; wv++) { c0 += hist[wv][2 * t]; c1 += hist[wv][2 * t + 1]; }
        p = c0 + c1;
        v = p;
        for (int off = 1; off < 64; off <<= 1) {
            unsigned u = __shfl_up(v, off);
            if (lane >= off) v += u;
        }
        if (lane == 63) scanw[wid] = v;
        __syncthreads();
        if (t < 16) {
            unsigned s = 0;
            for (int i = 0; i <= t; i++) s += scanw[i];
            scanw[16 + t] = s;
        }
        __syncthreads();
        incl = v + ((wid == 0) ? 0u : scanw[16 + wid - 1]);
        excl = incl - p;
        if (excl <= r0 && r0 < excl + c0)           s_v0 = lo2 + ((float)(2 * t) + 0.5f) * binw2;
        else if (excl + c0 <= r0 && r0 < incl)      s_v0 = lo2 + ((float)(2 * t + 1) + 0.5f) * binw2;
        if (excl <= r1 && r1 < excl + c0)           s_v1 = lo2 + ((float)(2 * t) + 0.5f) * binw2;
        else if (excl + c0 <= r1 && r1 < incl)      s_v1 = lo2 + ((float)(2 * t + 1) + 0.5f) * binw2;
        __syncthreads();
        med = 0.5f * (s_v0 + s_v1);
    }

    if (t == 0) {
        float hh = med / (2.0f * logf((float)(NP + 1)));
        float s = sqrtf(hh);
        float e1 = EMA[1], e0 = EMA[0];
        s = e1 * s + (1.f - e1) * e0;
        sig[0] = s;
        sig[1] = 1.f / (2.f * s * s);
        sig[2] = 1.f / (s * s);
        *sigma_out = s;
    }
}

// ---------------- k from G,sq; kout fp32 + kbF (diag-folded A-fragments) + ksum ----------------
__global__ __launch_bounds__(256) void kexp_kernel(const float* __restrict__ G,
                                                   const float* __restrict__ sq,
                                                   const float* __restrict__ sig,
                                                   float* __restrict__ kout,
                                                   unsigned short* __restrict__ kbF,
                                                   float* __restrict__ ksum) {
    int j = blockIdx.x, i = threadIdx.x;
    float d = fmaxf(sq[i] + sq[j] - 2.f * G[j * NP + i], 0.f);
    float kv = expf(-d * sig[1]);
    kout[j * NP + i] = kv;
    float s = kv;
    for (int off = 32; off > 0; off >>= 1) s += __shfl_down(s, off);
    __shared__ float wsum[4];
    int lane = i & 63, w = i >> 6;
    if (lane == 0) wsum[w] = s;
    __syncthreads();
    float ks = wsum[0] + wsum[1] + wsum[2] + wsum[3];
    if (i == 0) ksum[j] = ks;
    if (kbF) {
        float kstore = (i == j) ? (kv - ks) : kv;
        int chunk = (j >> 5) * 16 + (i >> 4);
        int lanee = ((i >> 3) & 1) * 32 + (j & 31);
        kbF[chunk * 512 + lanee * 8 + (i & 7)] = f2bf(kstore);
    }
}

// ---------------- der: pure GEMM x invs2 (diag-folded kbF), acc[2][2], 8 waves ----------------
__global__ __launch_bounds__(512) void der_mfma(const unsigned short* __restrict__ kbF,
                                                const unsigned short* __restrict__ XbTF,
                                                const float* __restrict__ sig,
                                                float* __restrict__ der) {
    const int t = threadIdx.x;
    const int lane = t & 63, w = t >> 6;
    const int wj = w >> 2, wd = w & 3;
    const int bx = blockIdx.x, by = blockIdx.y;

    f32x16 acc[2][2] = {};
    const unsigned short* pA[2];
    const unsigned short* pB[2];
#pragma unroll
    for (int s = 0; s < 2; s++)
        pA[s] = &kbF[(size_t)((by * 4 + wj * 2 + s) * 16) * 512 + lane * 8];
#pragma unroll
    for (int u = 0; u < 2; u++)
        pB[u] = &XbTF[(size_t)((bx * 8 + wd * 2 + u) * 16) * 512 + lane * 8];

#pragma unroll 4
    for (int i16 = 0; i16 < 16; i16++) {
        bf16x8 a[2], b[2];
#pragma unroll
        for (int s = 0; s < 2; s++) a[s] = *(const bf16x8*)(pA[s] + i16 * 512);
#pragma unroll
        for (int u = 0; u < 2; u++) b[u] = *(const bf16x8*)(pB[u] + i16 * 512);
#pragma unroll
        for (int s = 0; s < 2; s++)
#pragma unroll
            for (int u = 0; u < 2; u++)
                acc[s][u] = __builtin_amdgcn_mfma_f32_32x32x16_bf16(a[s], b[u], acc[s][u], 0, 0, 0);
    }
    const int hl = lane >> 5, lr = lane & 31;
    const float invs2 = sig[2];
#pragma unroll
    for (int u = 0; u < 2; u++) {
        const int dcol = bx * 256 + wd * 64 + u * 32 + lr;
#pragma unroll
        for (int s = 0; s < 2; s++) {
            const int jt = by * 128 + wj * 64 + s * 32;
#pragma unroll
            for (int q = 0; q < 4; q++) {
                int jq = jt + q * 8 + 4 * hl;
                der[(size_t)(jq + 0) * DD + dcol] = acc[s][u][q * 4 + 0] * invs2;
                der[(size_t)(jq + 1) * DD + dcol] = acc[s][u][q * 4 + 1] * invs2;
                der[(size_t)(jq + 2) * DD + dcol] = acc[s][u][q * 4 + 2] * invs2;
                der[(size_t)(jq + 3) * DD + dcol] = acc[s][u][q * 4 + 3] * invs2;
            }
        }
    }
}

// ================= fallback fp32 path (ws too small) =================
__global__ __launch_bounds__(256) void gram_kernel(const float* __restrict__ X,
                                                   float* __restrict__ G) {
    __shared__ __align__(16) float As[32][72];
    __shared__ __align__(16) float Bs[32][72];
    const int i0 = blockIdx.x * 64;
    const int j0 = blockIdx.y * 64;
    const int k0 = blockIdx.z * 2048;
    const int t  = threadIdx.x;
    const int tx = t & 15, ty = t >> 4;
    float acc[4][4];
#pragma unroll
    for (int q = 0; q < 4; q++)
#pragma unroll
        for (int r = 0; r < 4; r++) acc[q][r] = 0.f;
    for (int kb = k0; kb < k0 + 2048; kb += 32) {
#pragma unroll
        for (int u = 0; u < 2; u++) {
            int f = t * 2 + u, row = f >> 3, c4 = (f & 7) * 4;
            float4 av = *(const float4*)&X[(size_t)(i0 + row) * DD + kb + c4];
            As[c4 + 0][row] = av.x; As[c4 + 1][row] = av.y;
            As[c4 + 2][row] = av.z; As[c4 + 3][row] = av.w;
            float4 bvv = *(const float4*)&X[(size_t)(j0 + row) * DD + kb + c4];
            Bs[c4 + 0][row] = bvv.x; Bs[c4 + 1][row] = bvv.y;
            Bs[c4 + 2][row] = bvv.z; Bs[c4 + 3][row] = bvv.w;
        }
        __syncthreads();
#pragma unroll
        for (int kk = 0; kk < 32; kk++) {
            float4 a4 = *(const float4*)&As[kk][ty * 4];
            float4 b4 = *(const float4*)&Bs[kk][tx * 4];
            acc[0][0] += a4.x * b4.x; acc[0][1] += a4.x * b4.y;
            acc[0][2] += a4.x * b4.z; acc[0][3] += a4.x * b4.w;
            acc[1][0] += a4.y * b4.x; acc[1][1] += a4.y * b4.y;
            acc[1][2] += a4.y * b4.z; acc[1][3] += a4.y * b4.w;
            acc[2][0] += a4.z * b4.x; acc[2][1] += a4.z * b4.y;
            acc[2][2] += a4.z * b4.z; acc[2][3] += a4.z * b4.w;
            acc[3][0] += a4.w * b4.x; acc[3][1] += a4.w * b4.y;
            acc[3][2] += a4.w * b4.z; acc[3][3] += a4.w * b4.w;
        }
        __syncthreads();
    }
#pragma unroll
    for (int q = 0; q < 4; q++)
#pragma unroll
        for (int r = 0; r < 4; r++)
            atomicAdd(&G[(size_t)(i0 + ty * 4 + q) * NP + j0 + tx * 4 + r], acc[q][r]);
}

__global__ __launch_bounds__(256) void der_kernel(const float* __restrict__ X,
                                                  const float* __restrict__ kmat,
                                                  const float* __restrict__ ksum,
                                                  const float* __restrict__ sig,
                                                  float* __restrict__ der) {
    const int j0 = blockIdx.y * 32;
    const int d0 = blockIdx.x * 512 + threadIdx.x * 2;
    const float invs2 = sig[2];
    float2 acc[32];
#pragma unroll
    for (int jl = 0; jl < 32; jl++) { acc[jl].x = 0.f; acc[jl].y = 0.f; }
    for (int i = 0; i < NP; i++) {
        float2 xv = *(const float2*)&X[(size_t)i * DD + d0];
        const float4* kr = (const float4*)&kmat[i * NP + j0];
#pragma unroll
        for (int q = 0; q < 8; q++) {
            float4 k4 = kr[q];
            acc[q * 4 + 0].x += k4.x * xv.x; acc[q * 4 + 0].y += k4.x * xv.y;
            acc[q * 4 + 1].x += k4.y * xv.x; acc[q * 4 + 1].y += k4.y * xv.y;
            acc[q * 4 + 2].x += k4.z * xv.x; acc[q * 4 + 2].y += k4.z * xv.y;
            acc[q * 4 + 3].x += k4.w * xv.x; acc[q * 4 + 3].y += k4.w * xv.y;
        }
    }
#pragma unroll
    for (int jl = 0; jl < 32; jl++) {
        int j = j0 + jl;
        float2 xj = *(const float2*)&X[(size_t)j * DD + d0];
        float ks = ksum[j];
        float2 o;
        o.x = (acc[jl].x - ks * xj.x) * invs2;
        o.y = (acc[jl].y - ks * xj.y) * invs2;
        *(float2*)&der[(size_t)j * DD + d0] = o;
    }
}

extern "C" void kernel_launch(void* const* d_in, const int* in_sizes, int n_in,
                              void* d_out, int out_size, void* d_ws, size_t ws_size,
                              hipStream_t stream) {
    const float* X   = (const float*)d_in[0];
    const float* EMA = (const float*)d_in[1];
    float* out = (float*)d_out;
    float* ws  = (float*)d_ws;

    float* G    = ws;
    float* sq   = ws + WS_SQ;
    float* ksum = ws + WS_KSUM;
    float* sig  = ws + WS_SIG;

    float* kout      = out;
    float* der       = out + NP * NP;
    float* sigma_out = out + out_size - 1;

    if (ws_size >= (size_t)WS_NEED_MID) {
        unsigned short* XbTF = (unsigned short*)((char*)d_ws + XBTF_BYTE_OFF);
        unsigned short* kbF  = (unsigned short*)((char*)d_ws + KBF_BYTE_OFF);
        float* P = der;   // 256 slabs x 256 KB = exactly der's region; lower-tri
                          // tiles written by fused_gram_cast, read by gram_reduce,
                          // then whole region overwritten by der_mfma.

        fused_gram_cast<<<512, 1024, 0, stream>>>(X, P, XbTF);
        gram_reduce<<<160, 64, 0, stream>>>(P, G);
        median_sigma_kernel<<<1, 1024, 0, stream>>>(G, EMA, sq, sig, sigma_out);
        kexp_kernel<<<NP, NP, 0, stream>>>(G, sq, sig, kout, kbF, ksum);
        der_mfma<<<dim3(256, 2), 512, 0, stream>>>(kbF, XbTF, sig, der);
    } else {
        hipMemsetAsync(G, 0, (size_t)NP * NP * sizeof(float), stream);
        gram_kernel<<<dim3(4, 4, 32), 256, 0, stream>>>(X, G);
        median_sigma_kernel<<<1, 1024, 0, stream>>>(G, EMA, sq, sig, sigma_out);
        kexp_kernel<<<NP, NP, 0, stream>>>(G, sq, sig, kout, nullptr, ksum);
        der_kernel<<<dim3(128, 8), 256, 0, stream>>>(X, kout, ksum, sig, der);
    }
}

// Round 17
// 99.313 us; speedup vs baseline: 1.0752x; 1.0752x over previous
//
#include <hip/hip_runtime.h>
#include <hip/hip_bf16.h>
#include <math.h>

#define NP 256
#define DD 65536

// ws float offsets
#define WS_SQ    65536          // 256
#define WS_KSUM  (65536 + 256)  // 256
#define WS_SIG   66048          // [0]=sigma [1]=1/(2s^2) [2]=1/s^2
// byte offsets
#define XBTF_BYTE_OFF  33818656u        // der B frags (d,k=i): 33,554,432 B
#define KBF_BYTE_OFF   67373088u        // der A frags (j,k=i, diag-folded): 131,072 B
#define WS_NEED_MID    67504160u
// gram K-partials: 256 slabs x 256x256 f32 = 64 MB = exactly d_out's der region.
// Only LOWER-TRIANGLE 64x64 wave tiles are written (10 of 16 per slab; upper
// tiles are bitwise mirrors by MFMA commutativity). Written by fused_gram_cast,
// read by gram_reduce (lower tiles, mirrored into upper G), then the whole
// region is overwritten by der_mfma. Deterministic.

typedef __attribute__((ext_vector_type(8))) short bf16x8;
typedef __attribute__((ext_vector_type(16))) float f32x16;

static __device__ __forceinline__ unsigned short f2bf(float f) {
    __hip_bfloat16 h = __float2bfloat16(f);
    return *reinterpret_cast<unsigned short*>(&h);
}

// ---------------- fused cast+gram v8: v6 (X read once) + lower-tri P stores ----------------
// grid (256): z = K-chunk of 256 d (4 subs x 64 d). 1024 thr = 16 waves (wy,wx in 4x4),
// each wave a 64x64 tile (acc[2][2] of 32x32) -> block computes the full 256x256 tile,
// but only waves with wy >= wx store P (upper tiles are bitwise mirrors).
// A-slab (256 rows x 64 d bf16, fragment layout, 32 KB) double-buffered; both MFMA
// operands read the SAME buffer (Gram symmetry) -> X fetched exactly once overall.
// Each block also emits XbTF for its d-slab by strided gather from the frag buffer.
__global__ __launch_bounds__(1024) void fused_gram_cast(const float* __restrict__ X,
                                                        float* __restrict__ P,
                                                        unsigned short* __restrict__ XbTF) {
    __shared__ __align__(16) unsigned short Afrag[2][32 * 512];  // 2 x 32 KB
    const int t = threadIdx.x;
    const int lane = t & 63, w = t >> 6;
    const int wy = w >> 2, wx = w & 3;
    const int z = blockIdx.x;
    const int dbase = z * 256;
    const int srow = t >> 2;              // 0..255 staging row
    const int sdc  = (t & 3) * 16;        // staging d-col (16 floats = one k16 chunk)

    f32x16 acc[2][2] = {};
    float4 p0, p1, p2, p3;

    {   // prologue loads (sub 0)
        const float4* s = (const float4*)&X[(size_t)srow * DD + dbase + sdc];
        p0 = s[0]; p1 = s[1]; p2 = s[2]; p3 = s[3];
    }
    for (int sub = 0; sub < 4; ++sub) {
        unsigned short* buf = Afrag[sub & 1];
        {   // stage regs -> frag layout (2 x b128 per thread)
            union { unsigned short u[16]; bf16x8 v[2]; } a;
            a.u[0]  = f2bf(p0.x); a.u[1]  = f2bf(p0.y); a.u[2]  = f2bf(p0.z); a.u[3]  = f2bf(p0.w);
            a.u[4]  = f2bf(p1.x); a.u[5]  = f2bf(p1.y); a.u[6]  = f2bf(p1.z); a.u[7]  = f2bf(p1.w);
            a.u[8]  = f2bf(p2.x); a.u[9]  = f2bf(p2.y); a.u[10] = f2bf(p2.z); a.u[11] = f2bf(p2.w);
            a.u[12] = f2bf(p3.x); a.u[13] = f2bf(p3.y); a.u[14] = f2bf(p3.z); a.u[15] = f2bf(p3.w);
            int ch = (srow >> 5) * 4 + (sdc >> 4);
            *(bf16x8*)&buf[ch * 512 +       (srow & 31) * 8] = a.v[0];
            *(bf16x8*)&buf[ch * 512 + 256 + (srow & 31) * 8] = a.v[1];
        }
        __syncthreads();
        if (sub < 3) {                    // prefetch next sub BEFORE compute
            const float4* s = (const float4*)&X[(size_t)srow * DD + dbase + (sub + 1) * 64 + sdc];
            p0 = s[0]; p1 = s[1]; p2 = s[2]; p3 = s[3];
        }
#pragma unroll
        for (int ksi = 0; ksi < 4; ksi++) {
            bf16x8 a[2], b[2];
#pragma unroll
            for (int s = 0; s < 2; s++)
                a[s] = *(const bf16x8*)&buf[((wy * 2 + s) * 4 + ksi) * 512 + lane * 8];
#pragma unroll
            for (int u = 0; u < 2; u++)
                b[u] = *(const bf16x8*)&buf[((wx * 2 + u) * 4 + ksi) * 512 + lane * 8];
#pragma unroll
            for (int s = 0; s < 2; s++)
#pragma unroll
                for (int u = 0; u < 2; u++)
                    acc[s][u] = __builtin_amdgcn_mfma_f32_32x32x16_bf16(a[s], b[u], acc[s][u], 0, 0, 0);
        }
        // ---- XbTF emission: 2048 b128 outputs, 2 per thread, gathered from buf ----
#pragma unroll
        for (int r = 0; r < 2; r++) {
            int oid = t + r * 1024;
            int ch_o = oid >> 6, slot = oid & 63;
            int db = ch_o >> 4, i16 = ch_o & 15;
            int dl = db * 32 + (slot & 31);
            int ibase = i16 * 16 + (slot >> 5) * 8;
            int ch_in = (ibase >> 5) * 4 + (dl >> 4);
            int half = ((dl >> 3) & 1) * 256;
            int dlo = dl & 7;
            union { unsigned short u[8]; bf16x8 v; } o;
#pragma unroll
            for (int e = 0; e < 8; e++)
                o.u[e] = buf[ch_in * 512 + half + ((ibase + e) & 31) * 8 + dlo];
            size_t gch = (size_t)(z * 8 + sub * 2 + db) * 16 + i16;
            *(bf16x8*)&XbTF[gch * 512 + slot * 8] = o.v;
        }
    }
    // ---- write P[z]: lower-triangle wave tiles only ----
    if (wy >= wx) {
        const int hl = lane >> 5, lr = lane & 31;
        float* Pz = P + (size_t)z * 65536;
#pragma unroll
        for (int s = 0; s < 2; s++) {
            int ibt = wy * 64 + s * 32 + 4 * hl;
#pragma unroll
            for (int u = 0; u < 2; u++) {
                int jc = wx * 64 + u * 32 + lr;
#pragma unroll
                for (int r = 0; r < 16; r++) {
                    int ir = ibt + (r & 3) + 8 * (r >> 2);
                    Pz[ir * 256 + jc] = acc[s][u][r];
                }
            }
        }
    }
}

// ---------------- reduce 256 K-partials (lower tiles) -> full G ----------------
// grid 160 x 64 thr: 10 lower 64x64 tiles x 1024 float4 slots.
__global__ __launch_bounds__(64) void gram_reduce(const float* __restrict__ P,
                                                  float* __restrict__ G) {
    const int bid = blockIdx.x;               // 0..159
    const int tile = bid >> 4;                // 0..9 (lower-tri row-major)
    const int slot = (bid & 15) * 64 + threadIdx.x;   // 0..1023
    int ty, tx;
    if (tile < 1)      { ty = 0; tx = tile; }
    else if (tile < 3) { ty = 1; tx = tile - 1; }
    else if (tile < 6) { ty = 2; tx = tile - 3; }
    else               { ty = 3; tx = tile - 6; }
    const int il = slot >> 4;                 // 0..63
    const int jq = (slot & 15) * 4;
    const int i = ty * 64 + il;
    const int j = tx * 64 + jq;
    const int e4 = i * 64 + (j >> 2);
    const float4* P4 = (const float4*)P;
    float4 s0 = {0.f, 0.f, 0.f, 0.f}, s1 = {0.f, 0.f, 0.f, 0.f};
#pragma unroll 4
    for (int z = 0; z < 256; z += 2) {
        float4 a = P4[(size_t)z * 16384 + e4];
        float4 b = P4[(size_t)(z + 1) * 16384 + e4];
        s0.x += a.x; s0.y += a.y; s0.z += a.z; s0.w += a.w;
        s1.x += b.x; s1.y += b.y; s1.z += b.z; s1.w += b.w;
    }
    float4 s = {s0.x + s1.x, s0.y + s1.y, s0.z + s1.z, s0.w + s1.w};
    ((float4*)G)[e4] = s;
    if (ty > tx) {                            // mirror into upper triangle
        G[(j + 0) * 256 + i] = s.x;
        G[(j + 1) * 256 + i] = s.y;
        G[(j + 2) * 256 + i] = s.z;
        G[(j + 3) * 256 + i] = s.w;
    }
}

// ---------------- median via 2-level histogram select, one launch ----------------
#define L1BINS 2048
__global__ __launch_bounds__(1024) void median_sigma_kernel(const float* __restrict__ G,
                                                            const float* __restrict__ EMA,
                                                            float* __restrict__ sq_ws,
                                                            float* __restrict__ sig,
                                                            float* __restrict__ sigma_out) {
    __shared__ unsigned hist[16][L1BINS];       // 128 KB, per-wave copies
    __shared__ unsigned scanw[48];
    __shared__ float sq_l[256];
    __shared__ float redf[32];
    __shared__ unsigned s_b0, s_b1, s_base0;
    __shared__ float s_v0, s_v1;
    const int t = threadIdx.x;
    const int lane = t & 63, wid = t >> 6;

    if (t < 256) { float v = G[t * (NP + 1)]; sq_l[t] = v; sq_ws[t] = v; }
    __syncthreads();
    const float4* G4 = (const float4*)G;

    float mn = 3.4e38f, mx = 0.f;
    for (int q = 0; q < 16; q++) {
        int idx4 = q * 1024 + t;
        float4 g = G4[idx4];
        int i = idx4 >> 6, jb = (idx4 * 4) & 255;
        float si = sq_l[i];
        float d0 = fmaxf(si + sq_l[jb + 0] - 2.f * g.x, 0.f);
        float d1 = fmaxf(si + sq_l[jb + 1] - 2.f * g.y, 0.f);
        float d2 = fmaxf(si + sq_l[jb + 2] - 2.f * g.z, 0.f);
        float d3 = fmaxf(si + sq_l[jb + 3] - 2.f * g.w, 0.f);
        mn = fminf(mn, fminf(fminf(d0, d1), fminf(d2, d3)));
        mx = fmaxf(mx, fmaxf(fmaxf(d0, d1), fmaxf(d2, d3)));
    }
    for (int off = 32; off; off >>= 1) {
        mn = fminf(mn, __shfl_down(mn, off));
        mx = fmaxf(mx, __shfl_down(mx, off));
    }
    if (lane == 0) { redf[wid] = mn; redf[16 + wid] = mx; }
    __syncthreads();
    if (t == 0) {
        float a = redf[0], b = redf[16];
        for (int i = 1; i < 16; i++) { a = fminf(a, redf[i]); b = fmaxf(b, redf[16 + i]); }
        redf[0] = a; redf[16] = b;
    }
    __syncthreads();
    const float mn0 = redf[0];
    const float rng = redf[16] - mn0;
    float med = mn0;

    if (rng > 0.f) {
        const float scale1 = (float)L1BINS * (1.f - 1e-6f) / rng;
        const float binw1 = rng / ((float)L1BINS * (1.f - 1e-6f));
        {
            uint4* h4 = (uint4*)hist;
            uint4 zz = {0u, 0u, 0u, 0u};
            for (int i = t; i < 16 * L1BINS / 4; i += 1024) h4[i] = zz;
        }
        __syncthreads();
        for (int q = 0; q < 16; q++) {
            int idx4 = q * 1024 + t;
            float4 g = G4[idx4];
            int i = idx4 >> 6, jb = (idx4 * 4) & 255;
            float si = sq_l[i];
            float dd[4];
            dd[0] = fmaxf(si + sq_l[jb + 0] - 2.f * g.x, 0.f);
            dd[1] = fmaxf(si + sq_l[jb + 1] - 2.f * g.y, 0.f);
            dd[2] = fmaxf(si + sq_l[jb + 2] - 2.f * g.z, 0.f);
            dd[3] = fmaxf(si + sq_l[jb + 3] - 2.f * g.w, 0.f);
#pragma unroll
            for (int e = 0; e < 4; e++) {
                int b = (int)((dd[e] - mn0) * scale1);
                b = min(max(b, 0), L1BINS - 1);
                atomicAdd(&hist[wid][b], 1u);
            }
        }
        __syncthreads();
        unsigned c0 = 0, c1 = 0;
#pragma unroll
        for (int wv = 0; wv < 16; wv++) { c0 += hist[wv][2 * t]; c1 += hist[wv][2 * t + 1]; }
        unsigned p = c0 + c1;
        unsigned v = p;
        for (int off = 1; off < 64; off <<= 1) {
            unsigned u = __shfl_up(v, off);
            if (lane >= off) v += u;
        }
        if (lane == 63) scanw[wid] = v;
        __syncthreads();
        if (t < 16) {
            unsigned s = 0;
            for (int i = 0; i <= t; i++) s += scanw[i];
            scanw[16 + t] = s;
        }
        __syncthreads();
        unsigned incl = v + ((wid == 0) ? 0u : scanw[16 + wid - 1]);
        unsigned excl = incl - p;
        if (excl <= 32767u && 32767u < excl + c0) { s_b0 = 2 * t;     s_base0 = excl; }
        else if (excl + c0 <= 32767u && 32767u < incl) { s_b0 = 2 * t + 1; s_base0 = excl + c0; }
        if (excl <= 32768u && 32768u < excl + c0) s_b1 = 2 * t;
        else if (excl + c0 <= 32768u && 32768u < incl) s_b1 = 2 * t + 1;
        __syncthreads();
        const unsigned b0 = s_b0, b1 = s_b1, base0 = s_base0;
        const float lo2 = mn0 + (float)b0 * binw1;
        const float span = (float)(b1 + 1 - b0) * binw1;
        const float scale2 = (float)L1BINS * (1.f - 1e-6f) / span;
        const float binw2 = span / ((float)L1BINS * (1.f - 1e-6f));
        {
            uint4* h4 = (uint4*)hist;
            uint4 zz = {0u, 0u, 0u, 0u};
            for (int i = t; i < 16 * L1BINS / 4; i += 1024) h4[i] = zz;
        }
        __syncthreads();
        for (int q = 0; q < 16; q++) {
            int idx4 = q * 1024 + t;
            float4 g = G4[idx4];
            int i = idx4 >> 6, jb = (idx4 * 4) & 255;
            float si = sq_l[i];
            float dd[4];
            dd[0] = fmaxf(si + sq_l[jb + 0] - 2.f * g.x, 0.f);
            dd[1] = fmaxf(si + sq_l[jb + 1] - 2.f * g.y, 0.f);
            dd[2] = fmaxf(si + sq_l[jb + 2] - 2.f * g.z, 0.f);
            dd[3] = fmaxf(si + sq_l[jb + 3] - 2.f * g.w, 0.f);
#pragma unroll
            for (int e = 0; e < 4; e++) {
                int b = (int)((dd[e] - mn0) * scale1);
                b = min(max(b, 0), L1BINS - 1);
                if (b >= (int)b0 && b <= (int)b1) {
                    int sb = (int)((dd[e] - lo2) * scale2);
                    sb = min(max(sb, 0), L1BINS - 1);
                    atomicAdd(&hist[wid][sb], 1u);
                }
            }
        }
        __syncthreads();
        const unsigned r0 = 32767u - base0, r1 = 32768u - base0;
        c0 = 0; c1 = 0;
#pragma unroll
        for (int wv = 0; wv < 16; wv++) { c0 += hist[wv][2 * t]; c1 += hist[wv][2 * t + 1]; }
        p = c0 + c1;
        v = p;
        for (int off = 1; off < 64; off <<= 1) {
            unsigned u = __shfl_up(v, off);
            if (lane >= off) v += u;
        }
        if (lane == 63) scanw[wid] = v;
        __syncthreads();
        if (t < 16) {
            unsigned s = 0;
            for (int i = 0; i <= t; i++) s += scanw[i];
            scanw[16 + t] = s;
        }
        __syncthreads();
        incl = v + ((wid == 0) ? 0u : scanw[16 + wid - 1]);
        excl = incl - p;
        if (excl <= r0 && r0 < excl + c0)           s_v0 = lo2 + ((float)(2 * t) + 0.5f) * binw2;
        else if (excl + c0 <= r0 && r0 < incl)      s_v0 = lo2 + ((float)(2 * t + 1) + 0.5f) * binw2;
        if (excl <= r1 && r1 < excl + c0)           s_v1 = lo2 + ((float)(2 * t) + 0.5f) * binw2;
        else if (excl + c0 <= r1 && r1 < incl)      s_v1 = lo2 + ((float)(2 * t + 1) + 0.5f) * binw2;
        __syncthreads();
        med = 0.5f * (s_v0 + s_v1);
    }

    if (t == 0) {
        float hh = med / (2.0f * logf((float)(NP + 1)));
        float s = sqrtf(hh);
        float e1 = EMA[1], e0 = EMA[0];
        s = e1 * s + (1.f - e1) * e0;
        sig[0] = s;
        sig[1] = 1.f / (2.f * s * s);
        sig[2] = 1.f / (s * s);
        *sigma_out = s;
    }
}

// ---------------- k from G,sq; kout fp32 + kbF (diag-folded A-fragments) + ksum ----------------
__global__ __launch_bounds__(256) void kexp_kernel(const float* __restrict__ G,
                                                   const float* __restrict__ sq,
                                                   const float* __restrict__ sig,
                                                   float* __restrict__ kout,
                                                   unsigned short* __restrict__ kbF,
                                                   float* __restrict__ ksum) {
    int j = blockIdx.x, i = threadIdx.x;
    float d = fmaxf(sq[i] + sq[j] - 2.f * G[j * NP + i], 0.f);
    float kv = expf(-d * sig[1]);
    kout[j * NP + i] = kv;
    float s = kv;
    for (int off = 32; off > 0; off >>= 1) s += __shfl_down(s, off);
    __shared__ float wsum[4];
    int lane = i & 63, w = i >> 6;
    if (lane == 0) wsum[w] = s;
    __syncthreads();
    float ks = wsum[0] + wsum[1] + wsum[2] + wsum[3];
    if (i == 0) ksum[j] = ks;
    if (kbF) {
        float kstore = (i == j) ? (kv - ks) : kv;
        int chunk = (j >> 5) * 16 + (i >> 4);
        int lanee = ((i >> 3) & 1) * 32 + (j & 31);
        kbF[chunk * 512 + lanee * 8 + (i & 7)] = f2bf(kstore);
    }
}

// ---------------- der: pure GEMM x invs2 (diag-folded kbF), acc[2][2], 8 waves ----------------
__global__ __launch_bounds__(512) void der_mfma(const unsigned short* __restrict__ kbF,
                                                const unsigned short* __restrict__ XbTF,
                                                const float* __restrict__ sig,
                                                float* __restrict__ der) {
    const int t = threadIdx.x;
    const int lane = t & 63, w = t >> 6;
    const int wj = w >> 2, wd = w & 3;
    const int bx = blockIdx.x, by = blockIdx.y;

    f32x16 acc[2][2] = {};
    const unsigned short* pA[2];
    const unsigned short* pB[2];
#pragma unroll
    for (int s = 0; s < 2; s++)
        pA[s] = &kbF[(size_t)((by * 4 + wj * 2 + s) * 16) * 512 + lane * 8];
#pragma unroll
    for (int u = 0; u < 2; u++)
        pB[u] = &XbTF[(size_t)((bx * 8 + wd * 2 + u) * 16) * 512 + lane * 8];

#pragma unroll 4
    for (int i16 = 0; i16 < 16; i16++) {
        bf16x8 a[2], b[2];
#pragma unroll
        for (int s = 0; s < 2; s++) a[s] = *(const bf16x8*)(pA[s] + i16 * 512);
#pragma unroll
        for (int u = 0; u < 2; u++) b[u] = *(const bf16x8*)(pB[u] + i16 * 512);
#pragma unroll
        for (int s = 0; s < 2; s++)
#pragma unroll
            for (int u = 0; u < 2; u++)
                acc[s][u] = __builtin_amdgcn_mfma_f32_32x32x16_bf16(a[s], b[u], acc[s][u], 0, 0, 0);
    }
    const int hl = lane >> 5, lr = lane & 31;
    const float invs2 = sig[2];
#pragma unroll
    for (int u = 0; u < 2; u++) {
        const int dcol = bx * 256 + wd * 64 + u * 32 + lr;
#pragma unroll
        for (int s = 0; s < 2; s++) {
            const int jt = by * 128 + wj * 64 + s * 32;
#pragma unroll
            for (int q = 0; q < 4; q++) {
                int jq = jt + q * 8 + 4 * hl;
                der[(size_t)(jq + 0) * DD + dcol] = acc[s][u][q * 4 + 0] * invs2;
                der[(size_t)(jq + 1) * DD + dcol] = acc[s][u][q * 4 + 1] * invs2;
                der[(size_t)(jq + 2) * DD + dcol] = acc[s][u][q * 4 + 2] * invs2;
                der[(size_t)(jq + 3) * DD + dcol] = acc[s][u][q * 4 + 3] * invs2;
            }
        }
    }
}

// ================= fallback fp32 path (ws too small) =================
__global__ __launch_bounds__(256) void gram_kernel(const float* __restrict__ X,
                                                   float* __restrict__ G) {
    __shared__ __align__(16) float As[32][72];
    __shared__ __align__(16) float Bs[32][72];
    const int i0 = blockIdx.x * 64;
    const int j0 = blockIdx.y * 64;
    const int k0 = blockIdx.z * 2048;
    const int t  = threadIdx.x;
    const int tx = t & 15, ty = t >> 4;
    float acc[4][4];
#pragma unroll
    for (int q = 0; q < 4; q++)
#pragma unroll
        for (int r = 0; r < 4; r++) acc[q][r] = 0.f;
    for (int kb = k0; kb < k0 + 2048; kb += 32) {
#pragma unroll
        for (int u = 0; u < 2; u++) {
            int f = t * 2 + u, row = f >> 3, c4 = (f & 7) * 4;
            float4 av = *(const float4*)&X[(size_t)(i0 + row) * DD + kb + c4];
            As[c4 + 0][row] = av.x; As[c4 + 1][row] = av.y;
            As[c4 + 2][row] = av.z; As[c4 + 3][row] = av.w;
            float4 bvv = *(const float4*)&X[(size_t)(j0 + row) * DD + kb + c4];
            Bs[c4 + 0][row] = bvv.x; Bs[c4 + 1][row] = bvv.y;
            Bs[c4 + 2][row] = bvv.z; Bs[c4 + 3][row] = bvv.w;
        }
        __syncthreads();
#pragma unroll
        for (int kk = 0; kk < 32; kk++) {
            float4 a4 = *(const float4*)&As[kk][ty * 4];
            float4 b4 = *(const float4*)&Bs[kk][tx * 4];
            acc[0][0] += a4.x * b4.x; acc[0][1] += a4.x * b4.y;
            acc[0][2] += a4.x * b4.z; acc[0][3] += a4.x * b4.w;
            acc[1][0] += a4.y * b4.x; acc[1][1] += a4.y * b4.y;
            acc[1][2] += a4.y * b4.z; acc[1][3] += a4.y * b4.w;
            acc[2][0] += a4.z * b4.x; acc[2][1] += a4.z * b4.y;
            acc[2][2] += a4.z * b4.z; acc[2][3] += a4.z * b4.w;
            acc[3][0] += a4.w * b4.x; acc[3][1] += a4.w * b4.y;
            acc[3][2] += a4.w * b4.z; acc[3][3] += a4.w * b4.w;
        }
        __syncthreads();
    }
#pragma unroll
    for (int q = 0; q < 4; q++)
#pragma unroll
        for (int r = 0; r < 4; r++)
            atomicAdd(&G[(size_t)(i0 + ty * 4 + q) * NP + j0 + tx * 4 + r], acc[q][r]);
}

__global__ __launch_bounds__(256) void der_kernel(const float* __restrict__ X,
                                                  const float* __restrict__ kmat,
                                                  const float* __restrict__ ksum,
                                                  const float* __restrict__ sig,
                                                  float* __restrict__ der) {
    const int j0 = blockIdx.y * 32;
    const int d0 = blockIdx.x * 512 + threadIdx.x * 2;
    const float invs2 = sig[2];
    float2 acc[32];
#pragma unroll
    for (int jl = 0; jl < 32; jl++) { acc[jl].x = 0.f; acc[jl].y = 0.f; }
    for (int i = 0; i < NP; i++) {
        float2 xv = *(const float2*)&X[(size_t)i * DD + d0];
        const float4* kr = (const float4*)&kmat[i * NP + j0];
#pragma unroll
        for (int q = 0; q < 8; q++) {
            float4 k4 = kr[q];
            acc[q * 4 + 0].x += k4.x * xv.x; acc[q * 4 + 0].y += k4.x * xv.y;
            acc[q * 4 + 1].x += k4.y * xv.x; acc[q * 4 + 1].y += k4.y * xv.y;
            acc[q * 4 + 2].x += k4.z * xv.x; acc[q * 4 + 2].y += k4.z * xv.y;
            acc[q * 4 + 3].x += k4.w * xv.x; acc[q * 4 + 3].y += k4.w * xv.y;
        }
    }
#pragma unroll
    for (int jl = 0; jl < 32; jl++) {
        int j = j0 + jl;
        float2 xj = *(const float2*)&X[(size_t)j * DD + d0];
        float ks = ksum[j];
        float2 o;
        o.x = (acc[jl].x - ks * xj.x) * invs2;
        o.y = (acc[jl].y - ks * xj.y) * invs2;
        *(float2*)&der[(size_t)j * DD + d0] = o;
    }
}

extern "C" void kernel_launch(void* const* d_in, const int* in_sizes, int n_in,
                              void* d_out, int out_size, void* d_ws, size_t ws_size,
                              hipStream_t stream) {
    const float* X   = (const float*)d_in[0];
    const float* EMA = (const float*)d_in[1];
    float* out = (float*)d_out;
    float* ws  = (float*)d_ws;

    float* G    = ws;
    float* sq   = ws + WS_SQ;
    float* ksum = ws + WS_KSUM;
    float* sig  = ws + WS_SIG;

    float* kout      = out;
    float* der       = out + NP * NP;
    float* sigma_out = out + out_size - 1;

    if (ws_size >= (size_t)WS_NEED_MID) {
        unsigned short* XbTF = (unsigned short*)((char*)d_ws + XBTF_BYTE_OFF);
        unsigned short* kbF  = (unsigned short*)((char*)d_ws + KBF_BYTE_OFF);
        float* P = der;   // 256 slabs x 256 KB = exactly der's region; lower-tri
                          // wave tiles written by fused_gram_cast, read by
                          // gram_reduce, then whole region overwritten by der_mfma.

        fused_gram_cast<<<256, 1024, 0, stream>>>(X, P, XbTF);
        gram_reduce<<<160, 64, 0, stream>>>(P, G);
        median_sigma_kernel<<<1, 1024, 0, stream>>>(G, EMA, sq, sig, sigma_out);
        kexp_kernel<<<NP, NP, 0, stream>>>(G, sq, sig, kout, kbF, ksum);
        der_mfma<<<dim3(256, 2), 512, 0, stream>>>(kbF, XbTF, sig, der);
    } else {
        hipMemsetAsync(G, 0, (size_t)NP * NP * sizeof(float), stream);
        gram_kernel<<<dim3(4, 4, 32), 256, 0, stream>>>(X, G);
        median_sigma_kernel<<<1, 1024, 0, stream>>>(G, EMA, sq, sig, sigma_out);
        kexp_kernel<<<NP, NP, 0, stream>>>(G, sq, sig, kout, nullptr, ksum);
        der_kernel<<<dim3(128, 8), 256, 0, stream>>>(X, kout, ksum, sig, der);
    }
}

// Round 18
// 90.257 us; speedup vs baseline: 1.1831x; 1.1003x over previous
//
#include <hip/hip_runtime.h>
#include <hip/hip_bf16.h>
#include <math.h>

#define NP 256
#define DD 65536

// ws float offsets
#define WS_SQ    65536          // 256
#define WS_KSUM  (65536 + 256)  // 256
#define WS_SIG   66048          // [0]=sigma [1]=1/(2s^2) [2]=1/s^2
// byte offsets
#define XBTF_BYTE_OFF  33818656u        // der B frags (d,k=i): 33,554,432 B
#define KBF_BYTE_OFF   67373088u        // der A frags (j,k=i, diag-folded): 131,072 B
#define WS_NEED_MID    67504160u
// gram K-partials: 256 slabs x 256x256 BF16 = 32 MB inside d_out's der region.
// Only LOWER-TRIANGLE 64x64 wave tiles are written (upper are bitwise mirrors).
// bf16 partial rounding adds ~±14 (3sigma) to G diag / ~±1 off-diag -> dists
// err ~±20 -> k err ~8e-4, below the bf16 quantization (4e-3) already applied
// to k in kbF. Written by fused_gram_cast, read by gram_reduce, then the whole
// region is overwritten by der_mfma. Deterministic.

typedef __attribute__((ext_vector_type(8))) short bf16x8;
typedef __attribute__((ext_vector_type(16))) float f32x16;

static __device__ __forceinline__ unsigned short f2bf(float f) {
    __hip_bfloat16 h = __float2bfloat16(f);
    return *reinterpret_cast<unsigned short*>(&h);
}
static __device__ __forceinline__ float bf2f(unsigned short u) {
    return __uint_as_float((unsigned)u << 16);
}

// ---------------- fused cast+gram v9: v8 + bf16 P partials ----------------
// grid (256): z = K-chunk of 256 d (4 subs x 64 d). 1024 thr = 16 waves (wy,wx in 4x4),
// each wave a 64x64 tile (acc[2][2] of 32x32); only waves with wy >= wx store P.
// A-slab (256 rows x 64 d bf16, fragment layout, 32 KB) double-buffered; both MFMA
// operands read the SAME buffer (Gram symmetry) -> X fetched exactly once overall.
// Each block also emits XbTF for its d-slab by strided gather from the frag buffer.
__global__ __launch_bounds__(1024) void fused_gram_cast(const float* __restrict__ X,
                                                        unsigned short* __restrict__ P,
                                                        unsigned short* __restrict__ XbTF) {
    __shared__ __align__(16) unsigned short Afrag[2][32 * 512];  // 2 x 32 KB
    const int t = threadIdx.x;
    const int lane = t & 63, w = t >> 6;
    const int wy = w >> 2, wx = w & 3;
    const int z = blockIdx.x;
    const int dbase = z * 256;
    const int srow = t >> 2;              // 0..255 staging row
    const int sdc  = (t & 3) * 16;        // staging d-col (16 floats = one k16 chunk)

    f32x16 acc[2][2] = {};
    float4 p0, p1, p2, p3;

    {   // prologue loads (sub 0)
        const float4* s = (const float4*)&X[(size_t)srow * DD + dbase + sdc];
        p0 = s[0]; p1 = s[1]; p2 = s[2]; p3 = s[3];
    }
    for (int sub = 0; sub < 4; ++sub) {
        unsigned short* buf = Afrag[sub & 1];
        {   // stage regs -> frag layout (2 x b128 per thread)
            union { unsigned short u[16]; bf16x8 v[2]; } a;
            a.u[0]  = f2bf(p0.x); a.u[1]  = f2bf(p0.y); a.u[2]  = f2bf(p0.z); a.u[3]  = f2bf(p0.w);
            a.u[4]  = f2bf(p1.x); a.u[5]  = f2bf(p1.y); a.u[6]  = f2bf(p1.z); a.u[7]  = f2bf(p1.w);
            a.u[8]  = f2bf(p2.x); a.u[9]  = f2bf(p2.y); a.u[10] = f2bf(p2.z); a.u[11] = f2bf(p2.w);
            a.u[12] = f2bf(p3.x); a.u[13] = f2bf(p3.y); a.u[14] = f2bf(p3.z); a.u[15] = f2bf(p3.w);
            int ch = (srow >> 5) * 4 + (sdc >> 4);
            *(bf16x8*)&buf[ch * 512 +       (srow & 31) * 8] = a.v[0];
            *(bf16x8*)&buf[ch * 512 + 256 + (srow & 31) * 8] = a.v[1];
        }
        __syncthreads();
        if (sub < 3) {                    // prefetch next sub BEFORE compute
            const float4* s = (const float4*)&X[(size_t)srow * DD + dbase + (sub + 1) * 64 + sdc];
            p0 = s[0]; p1 = s[1]; p2 = s[2]; p3 = s[3];
        }
#pragma unroll
        for (int ksi = 0; ksi < 4; ksi++) {
            bf16x8 a[2], b[2];
#pragma unroll
            for (int s = 0; s < 2; s++)
                a[s] = *(const bf16x8*)&buf[((wy * 2 + s) * 4 + ksi) * 512 + lane * 8];
#pragma unroll
            for (int u = 0; u < 2; u++)
                b[u] = *(const bf16x8*)&buf[((wx * 2 + u) * 4 + ksi) * 512 + lane * 8];
#pragma unroll
            for (int s = 0; s < 2; s++)
#pragma unroll
                for (int u = 0; u < 2; u++)
                    acc[s][u] = __builtin_amdgcn_mfma_f32_32x32x16_bf16(a[s], b[u], acc[s][u], 0, 0, 0);
        }
        // ---- XbTF emission: 2048 b128 outputs, 2 per thread, gathered from buf ----
#pragma unroll
        for (int r = 0; r < 2; r++) {
            int oid = t + r * 1024;
            int ch_o = oid >> 6, slot = oid & 63;
            int db = ch_o >> 4, i16 = ch_o & 15;
            int dl = db * 32 + (slot & 31);
            int ibase = i16 * 16 + (slot >> 5) * 8;
            int ch_in = (ibase >> 5) * 4 + (dl >> 4);
            int half = ((dl >> 3) & 1) * 256;
            int dlo = dl & 7;
            union { unsigned short u[8]; bf16x8 v; } o;
#pragma unroll
            for (int e = 0; e < 8; e++)
                o.u[e] = buf[ch_in * 512 + half + ((ibase + e) & 31) * 8 + dlo];
            size_t gch = (size_t)(z * 8 + sub * 2 + db) * 16 + i16;
            *(bf16x8*)&XbTF[gch * 512 + slot * 8] = o.v;
        }
    }
    // ---- write P[z] (bf16): lower-triangle wave tiles only ----
    if (wy >= wx) {
        const int hl = lane >> 5, lr = lane & 31;
        unsigned short* Pz = P + (size_t)z * 65536;
#pragma unroll
        for (int s = 0; s < 2; s++) {
            int ibt = wy * 64 + s * 32 + 4 * hl;
#pragma unroll
            for (int u = 0; u < 2; u++) {
                int jc = wx * 64 + u * 32 + lr;
#pragma unroll
                for (int r = 0; r < 16; r++) {
                    int ir = ibt + (r & 3) + 8 * (r >> 2);
                    Pz[ir * 256 + jc] = f2bf(acc[s][u][r]);
                }
            }
        }
    }
}

// ---------------- reduce 256 bf16 K-partials (lower tiles) -> full fp32 G ----------------
// grid 160 x 64 thr: 10 lower 64x64 tiles x 1024 4-elem slots.
__global__ __launch_bounds__(64) void gram_reduce(const unsigned short* __restrict__ P,
                                                  float* __restrict__ G) {
    const int bid = blockIdx.x;               // 0..159
    const int tile = bid >> 4;                // 0..9 (lower-tri row-major)
    const int slot = (bid & 15) * 64 + threadIdx.x;   // 0..1023
    int ty, tx;
    if (tile < 1)      { ty = 0; tx = tile; }
    else if (tile < 3) { ty = 1; tx = tile - 1; }
    else if (tile < 6) { ty = 2; tx = tile - 3; }
    else               { ty = 3; tx = tile - 6; }
    const int il = slot >> 4;                 // 0..63
    const int jq = (slot & 15) * 4;
    const int i = ty * 64 + il;
    const int j = tx * 64 + jq;
    const int eoff = i * 256 + j;
    float4 s0 = {0.f, 0.f, 0.f, 0.f}, s1 = {0.f, 0.f, 0.f, 0.f};
#pragma unroll 4
    for (int z = 0; z < 256; z += 2) {
        ushort4 a = *(const ushort4*)&P[(size_t)z * 65536 + eoff];
        ushort4 b = *(const ushort4*)&P[(size_t)(z + 1) * 65536 + eoff];
        s0.x += bf2f(a.x); s0.y += bf2f(a.y); s0.z += bf2f(a.z); s0.w += bf2f(a.w);
        s1.x += bf2f(b.x); s1.y += bf2f(b.y); s1.z += bf2f(b.z); s1.w += bf2f(b.w);
    }
    float4 s = {s0.x + s1.x, s0.y + s1.y, s0.z + s1.z, s0.w + s1.w};
    *(float4*)&G[eoff] = s;
    if (ty > tx) {                            // mirror into upper triangle
        G[(j + 0) * 256 + i] = s.x;
        G[(j + 1) * 256 + i] = s.y;
        G[(j + 2) * 256 + i] = s.z;
        G[(j + 3) * 256 + i] = s.w;
    }
}

// ---------------- median via 2-level histogram select, one launch ----------------
#define L1BINS 2048
__global__ __launch_bounds__(1024) void median_sigma_kernel(const float* __restrict__ G,
                                                            const float* __restrict__ EMA,
                                                            float* __restrict__ sq_ws,
                                                            float* __restrict__ sig,
                                                            float* __restrict__ sigma_out) {
    __shared__ unsigned hist[16][L1BINS];       // 128 KB, per-wave copies
    __shared__ unsigned scanw[48];
    __shared__ float sq_l[256];
    __shared__ float redf[32];
    __shared__ unsigned s_b0, s_b1, s_base0;
    __shared__ float s_v0, s_v1;
    const int t = threadIdx.x;
    const int lane = t & 63, wid = t >> 6;

    if (t < 256) { float v = G[t * (NP + 1)]; sq_l[t] = v; sq_ws[t] = v; }
    __syncthreads();
    const float4* G4 = (const float4*)G;

    float mn = 3.4e38f, mx = 0.f;
    for (int q = 0; q < 16; q++) {
        int idx4 = q * 1024 + t;
        float4 g = G4[idx4];
        int i = idx4 >> 6, jb = (idx4 * 4) & 255;
        float si = sq_l[i];
        float d0 = fmaxf(si + sq_l[jb + 0] - 2.f * g.x, 0.f);
        float d1 = fmaxf(si + sq_l[jb + 1] - 2.f * g.y, 0.f);
        float d2 = fmaxf(si + sq_l[jb + 2] - 2.f * g.z, 0.f);
        float d3 = fmaxf(si + sq_l[jb + 3] - 2.f * g.w, 0.f);
        mn = fminf(mn, fminf(fminf(d0, d1), fminf(d2, d3)));
        mx = fmaxf(mx, fmaxf(fmaxf(d0, d1), fmaxf(d2, d3)));
    }
    for (int off = 32; off; off >>= 1) {
        mn = fminf(mn, __shfl_down(mn, off));
        mx = fmaxf(mx, __shfl_down(mx, off));
    }
    if (lane == 0) { redf[wid] = mn; redf[16 + wid] = mx; }
    __syncthreads();
    if (t == 0) {
        float a = redf[0], b = redf[16];
        for (int i = 1; i < 16; i++) { a = fminf(a, redf[i]); b = fmaxf(b, redf[16 + i]); }
        redf[0] = a; redf[16] = b;
    }
    __syncthreads();
    const float mn0 = redf[0];
    const float rng = redf[16] - mn0;
    float med = mn0;

    if (rng > 0.f) {
        const float scale1 = (float)L1BINS * (1.f - 1e-6f) / rng;
        const float binw1 = rng / ((float)L1BINS * (1.f - 1e-6f));
        {
            uint4* h4 = (uint4*)hist;
            uint4 zz = {0u, 0u, 0u, 0u};
            for (int i = t; i < 16 * L1BINS / 4; i += 1024) h4[i] = zz;
        }
        __syncthreads();
        for (int q = 0; q < 16; q++) {
            int idx4 = q * 1024 + t;
            float4 g = G4[idx4];
            int i = idx4 >> 6, jb = (idx4 * 4) & 255;
            float si = sq_l[i];
            float dd[4];
            dd[0] = fmaxf(si + sq_l[jb + 0] - 2.f * g.x, 0.f);
            dd[1] = fmaxf(si + sq_l[jb + 1] - 2.f * g.y, 0.f);
            dd[2] = fmaxf(si + sq_l[jb + 2] - 2.f * g.z, 0.f);
            dd[3] = fmaxf(si + sq_l[jb + 3] - 2.f * g.w, 0.f);
#pragma unroll
            for (int e = 0; e < 4; e++) {
                int b = (int)((dd[e] - mn0) * scale1);
                b = min(max(b, 0), L1BINS - 1);
                atomicAdd(&hist[wid][b], 1u);
            }
        }
        __syncthreads();
        unsigned c0 = 0, c1 = 0;
#pragma unroll
        for (int wv = 0; wv < 16; wv++) { c0 += hist[wv][2 * t]; c1 += hist[wv][2 * t + 1]; }
        unsigned p = c0 + c1;
        unsigned v = p;
        for (int off = 1; off < 64; off <<= 1) {
            unsigned u = __shfl_up(v, off);
            if (lane >= off) v += u;
        }
        if (lane == 63) scanw[wid] = v;
        __syncthreads();
        if (t < 16) {
            unsigned s = 0;
            for (int i = 0; i <= t; i++) s += scanw[i];
            scanw[16 + t] = s;
        }
        __syncthreads();
        unsigned incl = v + ((wid == 0) ? 0u : scanw[16 + wid - 1]);
        unsigned excl = incl - p;
        if (excl <= 32767u && 32767u < excl + c0) { s_b0 = 2 * t;     s_base0 = excl; }
        else if (excl + c0 <= 32767u && 32767u < incl) { s_b0 = 2 * t + 1; s_base0 = excl + c0; }
        if (excl <= 32768u && 32768u < excl + c0) s_b1 = 2 * t;
        else if (excl + c0 <= 32768u && 32768u < incl) s_b1 = 2 * t + 1;
        __syncthreads();
        const unsigned b0 = s_b0, b1 = s_b1, base0 = s_base0;
        const float lo2 = mn0 + (float)b0 * binw1;
        const float span = (float)(b1 + 1 - b0) * binw1;
        const float scale2 = (float)L1BINS * (1.f - 1e-6f) / span;
        const float binw2 = span / ((float)L1BINS * (1.f - 1e-6f));
        {
            uint4* h4 = (uint4*)hist;
            uint4 zz = {0u, 0u, 0u, 0u};
            for (int i = t; i < 16 * L1BINS / 4; i += 1024) h4[i] = zz;
        }
        __syncthreads();
        for (int q = 0; q < 16; q++) {
            int idx4 = q * 1024 + t;
            float4 g = G4[idx4];
            int i = idx4 >> 6, jb = (idx4 * 4) & 255;
            float si = sq_l[i];
            float dd[4];
            dd[0] = fmaxf(si + sq_l[jb + 0] - 2.f * g.x, 0.f);
            dd[1] = fmaxf(si + sq_l[jb + 1] - 2.f * g.y, 0.f);
            dd[2] = fmaxf(si + sq_l[jb + 2] - 2.f * g.z, 0.f);
            dd[3] = fmaxf(si + sq_l[jb + 3] - 2.f * g.w, 0.f);
#pragma unroll
            for (int e = 0; e < 4; e++) {
                int b = (int)((dd[e] - mn0) * scale1);
                b = min(max(b, 0), L1BINS - 1);
                if (b >= (int)b0 && b <= (int)b1) {
                    int sb = (int)((dd[e] - lo2) * scale2);
                    sb = min(max(sb, 0), L1BINS - 1);
                    atomicAdd(&hist[wid][sb], 1u);
                }
            }
        }
        __syncthreads();
        const unsigned r0 = 32767u - base0, r1 = 32768u - base0;
        c0 = 0; c1 = 0;
#pragma unroll
        for (int wv = 0; wv < 16; wv++) { c0 += hist[wv][2 * t]; c1 += hist[wv][2 * t + 1]; }
        p = c0 + c1;
        v = p;
        for (int off = 1; off < 64; off <<= 1) {
            unsigned u = __shfl_up(v, off);
            if (lane >= off) v += u;
        }
        if (lane == 63) scanw[wid] = v;
        __syncthreads();
        if (t < 16) {
            unsigned s = 0;
            for (int i = 0; i <= t; i++) s += scanw[i];
            scanw[16 + t] = s;
        }
        __syncthreads();
        incl = v + ((wid == 0) ? 0u : scanw[16 + wid - 1]);
        excl = incl - p;
        if (excl <= r0 && r0 < excl + c0)           s_v0 = lo2 + ((float)(2 * t) + 0.5f) * binw2;
        else if (excl + c0 <= r0 && r0 < incl)      s_v0 = lo2 + ((float)(2 * t + 1) + 0.5f) * binw2;
        if (excl <= r1 && r1 < excl + c0)           s_v1 = lo2 + ((float)(2 * t) + 0.5f) * binw2;
        else if (excl + c0 <= r1 && r1 < incl)      s_v1 = lo2 + ((float)(2 * t + 1) + 0.5f) * binw2;
        __syncthreads();
        med = 0.5f * (s_v0 + s_v1);
    }

    if (t == 0) {
        float hh = med / (2.0f * logf((float)(NP + 1)));
        float s = sqrtf(hh);
        float e1 = EMA[1], e0 = EMA[0];
        s = e1 * s + (1.f - e1) * e0;
        sig[0] = s;
        sig[1] = 1.f / (2.f * s * s);
        sig[2] = 1.f / (s * s);
        *sigma_out = s;
    }
}

// ---------------- k from G,sq; kout fp32 + kbF (diag-folded A-fragments) + ksum ----------------
__global__ __launch_bounds__(256) void kexp_kernel(const float* __restrict__ G,
                                                   const float* __restrict__ sq,
                                                   const float* __restrict__ sig,
                                                   float* __restrict__ kout,
                                                   unsigned short* __restrict__ kbF,
                                                   float* __restrict__ ksum) {
    int j = blockIdx.x, i = threadIdx.x;
    float d = fmaxf(sq[i] + sq[j] - 2.f * G[j * NP + i], 0.f);
    float kv = expf(-d * sig[1]);
    kout[j * NP + i] = kv;
    float s = kv;
    for (int off = 32; off > 0; off >>= 1) s += __shfl_down(s, off);
    __shared__ float wsum[4];
    int lane = i & 63, w = i >> 6;
    if (lane == 0) wsum[w] = s;
    __syncthreads();
    float ks = wsum[0] + wsum[1] + wsum[2] + wsum[3];
    if (i == 0) ksum[j] = ks;
    if (kbF) {
        float kstore = (i == j) ? (kv - ks) : kv;
        int chunk = (j >> 5) * 16 + (i >> 4);
        int lanee = ((i >> 3) & 1) * 32 + (j & 31);
        kbF[chunk * 512 + lanee * 8 + (i & 7)] = f2bf(kstore);
    }
}

// ---------------- der: pure GEMM x invs2 (diag-folded kbF), acc[2][2], 8 waves ----------------
__global__ __launch_bounds__(512) void der_mfma(const unsigned short* __restrict__ kbF,
                                                const unsigned short* __restrict__ XbTF,
                                                const float* __restrict__ sig,
                                                float* __restrict__ der) {
    const int t = threadIdx.x;
    const int lane = t & 63, w = t >> 6;
    const int wj = w >> 2, wd = w & 3;
    const int bx = blockIdx.x, by = blockIdx.y;

    f32x16 acc[2][2] = {};
    const unsigned short* pA[2];
    const unsigned short* pB[2];
#pragma unroll
    for (int s = 0; s < 2; s++)
        pA[s] = &kbF[(size_t)((by * 4 + wj * 2 + s) * 16) * 512 + lane * 8];
#pragma unroll
    for (int u = 0; u < 2; u++)
        pB[u] = &XbTF[(size_t)((bx * 8 + wd * 2 + u) * 16) * 512 + lane * 8];

#pragma unroll 4
    for (int i16 = 0; i16 < 16; i16++) {
        bf16x8 a[2], b[2];
#pragma unroll
        for (int s = 0; s < 2; s++) a[s] = *(const bf16x8*)(pA[s] + i16 * 512);
#pragma unroll
        for (int u = 0; u < 2; u++) b[u] = *(const bf16x8*)(pB[u] + i16 * 512);
#pragma unroll
        for (int s = 0; s < 2; s++)
#pragma unroll
            for (int u = 0; u < 2; u++)
                acc[s][u] = __builtin_amdgcn_mfma_f32_32x32x16_bf16(a[s], b[u], acc[s][u], 0, 0, 0);
    }
    const int hl = lane >> 5, lr = lane & 31;
    const float invs2 = sig[2];
#pragma unroll
    for (int u = 0; u < 2; u++) {
        const int dcol = bx * 256 + wd * 64 + u * 32 + lr;
#pragma unroll
        for (int s = 0; s < 2; s++) {
            const int jt = by * 128 + wj * 64 + s * 32;
#pragma unroll
            for (int q = 0; q < 4; q++) {
                int jq = jt + q * 8 + 4 * hl;
                der[(size_t)(jq + 0) * DD + dcol] = acc[s][u][q * 4 + 0] * invs2;
                der[(size_t)(jq + 1) * DD + dcol] = acc[s][u][q * 4 + 1] * invs2;
                der[(size_t)(jq + 2) * DD + dcol] = acc[s][u][q * 4 + 2] * invs2;
                der[(size_t)(jq + 3) * DD + dcol] = acc[s][u][q * 4 + 3] * invs2;
            }
        }
    }
}

// ================= fallback fp32 path (ws too small) =================
__global__ __launch_bounds__(256) void gram_kernel(const float* __restrict__ X,
                                                   float* __restrict__ G) {
    __shared__ __align__(16) float As[32][72];
    __shared__ __align__(16) float Bs[32][72];
    const int i0 = blockIdx.x * 64;
    const int j0 = blockIdx.y * 64;
    const int k0 = blockIdx.z * 2048;
    const int t  = threadIdx.x;
    const int tx = t & 15, ty = t >> 4;
    float acc[4][4];
#pragma unroll
    for (int q = 0; q < 4; q++)
#pragma unroll
        for (int r = 0; r < 4; r++) acc[q][r] = 0.f;
    for (int kb = k0; kb < k0 + 2048; kb += 32) {
#pragma unroll
        for (int u = 0; u < 2; u++) {
            int f = t * 2 + u, row = f >> 3, c4 = (f & 7) * 4;
            float4 av = *(const float4*)&X[(size_t)(i0 + row) * DD + kb + c4];
            As[c4 + 0][row] = av.x; As[c4 + 1][row] = av.y;
            As[c4 + 2][row] = av.z; As[c4 + 3][row] = av.w;
            float4 bvv = *(const float4*)&X[(size_t)(j0 + row) * DD + kb + c4];
            Bs[c4 + 0][row] = bvv.x; Bs[c4 + 1][row] = bvv.y;
            Bs[c4 + 2][row] = bvv.z; Bs[c4 + 3][row] = bvv.w;
        }
        __syncthreads();
#pragma unroll
        for (int kk = 0; kk < 32; kk++) {
            float4 a4 = *(const float4*)&As[kk][ty * 4];
            float4 b4 = *(const float4*)&Bs[kk][tx * 4];
            acc[0][0] += a4.x * b4.x; acc[0][1] += a4.x * b4.y;
            acc[0][2] += a4.x * b4.z; acc[0][3] += a4.x * b4.w;
            acc[1][0] += a4.y * b4.x; acc[1][1] += a4.y * b4.y;
            acc[1][2] += a4.y * b4.z; acc[1][3] += a4.y * b4.w;
            acc[2][0] += a4.z * b4.x; acc[2][1] += a4.z * b4.y;
            acc[2][2] += a4.z * b4.z; acc[2][3] += a4.z * b4.w;
            acc[3][0] += a4.w * b4.x; acc[3][1] += a4.w * b4.y;
            acc[3][2] += a4.w * b4.z; acc[3][3] += a4.w * b4.w;
        }
        __syncthreads();
    }
#pragma unroll
    for (int q = 0; q < 4; q++)
#pragma unroll
        for (int r = 0; r < 4; r++)
            atomicAdd(&G[(size_t)(i0 + ty * 4 + q) * NP + j0 + tx * 4 + r], acc[q][r]);
}

__global__ __launch_bounds__(256) void der_kernel(const float* __restrict__ X,
                                                  const float* __restrict__ kmat,
                                                  const float* __restrict__ ksum,
                                                  const float* __restrict__ sig,
                                                  float* __restrict__ der) {
    const int j0 = blockIdx.y * 32;
    const int d0 = blockIdx.x * 512 + threadIdx.x * 2;
    const float invs2 = sig[2];
    float2 acc[32];
#pragma unroll
    for (int jl = 0; jl < 32; jl++) { acc[jl].x = 0.f; acc[jl].y = 0.f; }
    for (int i = 0; i < NP; i++) {
        float2 xv = *(const float2*)&X[(size_t)i * DD + d0];
        const float4* kr = (const float4*)&kmat[i * NP + j0];
#pragma unroll
        for (int q = 0; q < 8; q++) {
            float4 k4 = kr[q];
            acc[q * 4 + 0].x += k4.x * xv.x; acc[q * 4 + 0].y += k4.x * xv.y;
            acc[q * 4 + 1].x += k4.y * xv.x; acc[q * 4 + 1].y += k4.y * xv.y;
            acc[q * 4 + 2].x += k4.z * xv.x; acc[q * 4 + 2].y += k4.z * xv.y;
            acc[q * 4 + 3].x += k4.w * xv.x; acc[q * 4 + 3].y += k4.w * xv.y;
        }
    }
#pragma unroll
    for (int jl = 0; jl < 32; jl++) {
        int j = j0 + jl;
        float2 xj = *(const float2*)&X[(size_t)j * DD + d0];
        float ks = ksum[j];
        float2 o;
        o.x = (acc[jl].x - ks * xj.x) * invs2;
        o.y = (acc[jl].y - ks * xj.y) * invs2;
        *(float2*)&der[(size_t)j * DD + d0] = o;
    }
}

extern "C" void kernel_launch(void* const* d_in, const int* in_sizes, int n_in,
                              void* d_out, int out_size, void* d_ws, size_t ws_size,
                              hipStream_t stream) {
    const float* X   = (const float*)d_in[0];
    const float* EMA = (const float*)d_in[1];
    float* out = (float*)d_out;
    float* ws  = (float*)d_ws;

    float* G    = ws;
    float* sq   = ws + WS_SQ;
    float* ksum = ws + WS_KSUM;
    float* sig  = ws + WS_SIG;

    float* kout      = out;
    float* der       = out + NP * NP;
    float* sigma_out = out + out_size - 1;

    if (ws_size >= (size_t)WS_NEED_MID) {
        unsigned short* XbTF = (unsigned short*)((char*)d_ws + XBTF_BYTE_OFF);
        unsigned short* kbF  = (unsigned short*)((char*)d_ws + KBF_BYTE_OFF);
        unsigned short* P = (unsigned short*)der;  // 256 slabs x 128 KB bf16 = 32 MB
                          // inside der's 64 MB region; lower-tri wave tiles written
                          // by fused_gram_cast, read by gram_reduce, then the whole
                          // region is overwritten by der_mfma.

        fused_gram_cast<<<256, 1024, 0, stream>>>(X, P, XbTF);
        gram_reduce<<<160, 64, 0, stream>>>(P, G);
        median_sigma_kernel<<<1, 1024, 0, stream>>>(G, EMA, sq, sig, sigma_out);
        kexp_kernel<<<NP, NP, 0, stream>>>(G, sq, sig, kout, kbF, ksum);
        der_mfma<<<dim3(256, 2), 512, 0, stream>>>(kbF, XbTF, sig, der);
    } else {
        hipMemsetAsync(G, 0, (size_t)NP * NP * sizeof(float), stream);
        gram_kernel<<<dim3(4, 4, 32), 256, 0, stream>>>(X, G);
        median_sigma_kernel<<<1, 1024, 0, stream>>>(G, EMA, sq, sig, sigma_out);
        kexp_kernel<<<NP, NP, 0, stream>>>(G, sq, sig, kout, nullptr, ksum);
        der_kernel<<<dim3(128, 8), 256, 0, stream>>>(X, kout, ksum, sig, der);
    }
}